// Round 1
// baseline (361.585 us; speedup 1.0000x reference)
//
#include <hip/hip_runtime.h>
#include <hip/hip_fp16.h>
#include <math.h>

// Problem constants (from reference)
#define B_TRAJ 16384
#define T_STEPS 60
#define D_IN 36
#define L_DIM 10
#define C_NUM 20
#define S_STAT 9
#define OUT_DIM 8
#define TT 2
#define NTILE (T_STEPS / TT)   // 30

#define LOG2E 1.4426950408889634f

__device__ __forceinline__ float rcp_fast(float x) { return __builtin_amdgcn_rcpf(x); }
__device__ __forceinline__ float exp2_fast(float x) { return __builtin_amdgcn_exp2f(x); }
__device__ __forceinline__ float sigm_fast(float x) {
    // 1/(1+e^-x) = 1/(1+2^(-x*log2e)) : mul, exp, add, rcp
    return rcp_fast(1.0f + exp2_fast(x * -LOG2E));
}
__device__ __forceinline__ float tanh_fast(float x) {
    // tanh(x) = 1 - 2/(2^(2x*log2e)+1) : mul, min, max, exp, add, rcp, fma
    const float t = fminf(fmaxf(x * (2.0f * LOG2E), -30.0f), 30.0f);
    return fmaf(-2.0f, rcp_fast(exp2_fast(t) + 1.0f), 1.0f);
}
// DS-pinning scheduling fence: ALU/VALU/SALU/MFMA/VMEM may cross, DS may NOT.
// Cross-lane LDS ordering (write-before-read across lanes of a wave) only needs
// DS program order; letting VALU cross enables cross-step interleave with unroll.
#define SBAR() __builtin_amdgcn_sched_barrier(0x7F)

// Phase 1: per-wave precompute xproj[traj][t][c] = bias_c + x_t . Wx[:,c] (f16 in LDS).
// Phase 2: sequential scan, branch-free body; all cross-lane traffic via
//          unconditional LDS slots (disjoint per lane role) + ds_bpermute/ds_swizzle.
//          Softmax z is normalized at the PRODUCER (swizzle butterfly), so readers
//          need no zsum recompute. y_t written back (f16) into consumed xproj[t].
// Phase 3: deferred MLP head — 4 t-groups x 8 cols across 32 lanes, 2-shuffle reduce.
// Lane roles (s = lane & 31): s<10 u-col (+ODE col), 10..19 r-col (+emit col),
// 20..29 n-col (+emit col), 30/31 inert. All phase-2/3 sync is intra-wave
// (in-order LDS + DS-pinned sched_barrier).
__global__ __launch_bounds__(256) __attribute__((amdgpu_waves_per_eu(4, 8)))
void dgm2_v6(
    const float* __restrict__ data,        // [B, T, D]
    const float* __restrict__ time_steps,  // [T]
    const float* __restrict__ static_data, // [B, S]
    const float* __restrict__ W_update,    // [46, 10]
    const float* __restrict__ b_update,
    const float* __restrict__ W_reset,     // [46, 10]
    const float* __restrict__ b_reset,
    const float* __restrict__ W_new,       // [46, 10]
    const float* __restrict__ b_new,
    const float* __restrict__ W_emit,      // [30, 20]
    const float* __restrict__ b_emit,
    const float* __restrict__ W_ode,       // [10, 10]
    const float* __restrict__ b_ode,
    const float* __restrict__ W_mlp,       // [609, 8]
    const float* __restrict__ b_mlp,
    float* __restrict__ out)               // [B, 8]
{
    __shared__ __align__(16) __half xprojH[8][61][32];   // 31232 B (t-dim padded: halves 16 banks apart)
    __shared__ __align__(16) float WGX[D_IN][32];        // 4608 B (phase-1 x-weights, col per lane)
    __shared__ __align__(16) float wbuf[4][292];         // 4672 B per-wave scratch:
                                                          //  phase1: xstage [buf][half][tt][36] (288 f)
                                                          //  phase2: 4 x 64-slot bc buffers (256 f)
    __shared__ float dts[T_STEPS];

    const int tid  = threadIdx.x;
    const int w    = tid >> 6;
    const int lane = tid & 63;
    const int half = lane >> 5;
    const int s    = lane & 31;
    const int ltraj = w * 2 + half;
    const int traj  = blockIdx.x * 8 + ltraj;

    // ---- block-wide one-time: WGX + dts ----
    for (int i = tid; i < D_IN * 30; i += 256) {
        const int k = i / 30, c = i % 30;
        float v;
        if (c < 10)      v = W_update[(L_DIM + k) * L_DIM + c];
        else if (c < 20) v = W_reset [(L_DIM + k) * L_DIM + (c - 10)];
        else             v = W_new   [(L_DIM + k) * L_DIM + (c - 20)];
        WGX[k][c] = v;
    }
    for (int i = tid; i < D_IN * 2; i += 256) WGX[i >> 1][30 + (i & 1)] = 0.0f;
    if (tid < T_STEPS) dts[tid] = (tid == 0) ? 0.01f : time_steps[tid] - time_steps[tid - 1];
    __syncthreads();

    // per-lane gate-column bias, folded into xproj during phase 1
    float bcol = 0.0f;
    if (s < 10)      bcol = b_update[s];
    else if (s < 20) bcol = b_reset[s - 10];
    else if (s < 30) bcol = b_new[s - 20];

    // ================= Phase 1: xproj precompute (wave-local) =================
    {
        float wxp[D_IN];
#pragma unroll
        for (int k = 0; k < D_IN; ++k) wxp[k] = WGX[k][s];

        float* xst = &wbuf[w][0];   // [buf][half][tt][36]
        const float* tbase = data + (size_t)(blockIdx.x * 8 + w * 2) * (T_STEPS * D_IN);
        const int sh  = lane / 18;      // staging half
        const int sr  = lane % 18;
        const int stt = sr / 9;         // timestep within tile
        const int sc  = sr % 9;         // float4 chunk
        const bool stg = (lane < 36);

        if (stg) {
            const float4 v = *reinterpret_cast<const float4*>(
                tbase + (size_t)sh * (T_STEPS * D_IN) + stt * D_IN + sc * 4);
            *reinterpret_cast<float4*>(xst + ((0 * 2 + sh) * TT + stt) * 36 + sc * 4) = v;
        }
        SBAR();

        for (int tile = 0; tile < NTILE; ++tile) {
            const int cb = tile & 1, nb = cb ^ 1;
            float4 pf = make_float4(0.f, 0.f, 0.f, 0.f);
            if (stg && (tile + 1 < NTILE)) {
                pf = *reinterpret_cast<const float4*>(
                    tbase + (size_t)sh * (T_STEPS * D_IN) + ((tile + 1) * TT + stt) * D_IN + sc * 4);
            }
#pragma unroll
            for (int tt = 0; tt < TT; ++tt) {
                const float* xrow = xst + ((cb * 2 + half) * TT + tt) * 36;
                float acc = bcol;                       // gate bias folded here
#pragma unroll
                for (int c = 0; c < 9; ++c) {
                    const float4 x4 = *reinterpret_cast<const float4*>(xrow + c * 4);
                    acc += x4.x * wxp[c * 4]     + x4.y * wxp[c * 4 + 1]
                         + x4.z * wxp[c * 4 + 2] + x4.w * wxp[c * 4 + 3];
                }
                xprojH[ltraj][tile * TT + tt][s] = __float2half(acc);  // cols 30/31 = 0, unread
            }
            if (stg && (tile + 1 < NTILE)) {
                *reinterpret_cast<float4*>(xst + ((nb * 2 + sh) * TT + stt) * 36 + sc * 4) = pf;
            }
            SBAR();
        }
    }

    // ================= Phase 2: sequential scan =================
    const bool uo = (s < 10);
    const bool ro = (s >= 10 && s < 20);
    const bool no = (s >= 20 && s < 30);
    const bool eo = (s >= 10 && s < 30);
    const int  gcol = uo ? s : (ro ? (s - 10) : (no ? (s - 20) : 0));

    const float* Wg = uo ? W_update : (ro ? W_reset : W_new);
    float wgy[L_DIM];
#pragma unroll
    for (int k = 0; k < L_DIM; ++k) wgy[k] = (s < 30) ? Wg[k * L_DIM + gcol] : 0.0f;

    float waux[30];     // eo: emit col; uo: [0..9] = ODE col
#pragma unroll
    for (int k = 0; k < 30; ++k) {
        float v = 0.0f;
        if (eo) v = W_emit[k * C_NUM + (s - 10)];
        else if (uo && k < L_DIM) v = W_ode[k * L_DIM + s];
        waux[k] = v;
    }
    const float bode  = uo ? b_ode[s] : 0.0f;
    const float bemit = eo ? b_emit[s - 10] : 0.0f;

    // per-wave bc buffers: 4 x [2 halves][32 slots]; all-lane unconditional writes.
    // Writers map to disjoint slots; readers only touch the meaningful range.
    const int lanebase = half << 5;
    const int slotB = (s - 10) & 31;                    // ro/eo -> 0..19; uo -> 22..31; 30/31 -> 20/21
    const int nperm = (lanebase + (uo ? s + 20 : s)) << 2;   // uo reads n-lane's accN
    const int rperm = (lanebase + ((s - 10) & 31)) << 2;     // ro reads uo-lane's yis

    float* wb   = &wbuf[w][0];
    float* bcYI = wb       + lanebase;
    float* bcR  = wb + 64  + lanebase;
    float* bcY  = wb + 128 + lanebase;
    float* bcP  = wb + 192 + lanebase;

    float y[L_DIM];
#pragma unroll
    for (int k = 0; k < L_DIM; ++k) y[k] = 0.0f;
    float yown = 0.0f;
    bcP[slotB] = 0.0f;          // normalized p carried; 0 => p=0 at t=0
    SBAR();

#pragma unroll 2
    for (int t = 0; t < T_STEPS; ++t) {
        const float dt = dts[t];

        // ---- ODE: yi_s = y_s + tanh(b + y.Wode_col_s)*dt (meaningful on uo) ----
        float g = bode;
#pragma unroll
        for (int k = 0; k < L_DIM; ++k) g += y[k] * waux[k];
        const float yis = fmaf(tanh_fast(g), dt, yown);
        bcYI[s] = yis;
        SBAR();
        {
            const float4 a = *reinterpret_cast<const float4*>(bcYI);
            const float4 b = *reinterpret_cast<const float4*>(bcYI + 4);
            const float2 c = *reinterpret_cast<const float2*>(bcYI + 8);
            y[0] = a.x; y[1] = a.y; y[2] = a.z; y[3] = a.w;
            y[4] = b.x; y[5] = b.y; y[6] = b.z; y[7] = b.w;
            y[8] = c.x; y[9] = c.y;
        }
        // ro lane's own yi (register crossbar, no LDS dependency)
        const float yi_r = __int_as_float(__builtin_amdgcn_ds_bpermute(rperm, __float_as_int(yis)));

        // ---- gates: pre-activation = xproj(f16, bias folded) + y-part ----
        const float xa = __half2float(xprojH[ltraj][t][s]);
        float accY = xa;
#pragma unroll
        for (int k = 0; k < L_DIM; ++k) accY += y[k] * wgy[k];
        const float uval = sigm_fast(accY);   // u on uo, r on ro
        bcR[s] = uval * yi_r;                 // ro lanes publish yr_k = r_k*yi_k (slots 10..19)
        SBAR();

        // ---- candidate: xa + sum yr_k wn_k (meaningful on no lanes) ----
        float accN = xa;
        {
            const float4 a = *reinterpret_cast<const float4*>(bcR + 10 - 10); // yr in slots 10..19
            // NOTE: yr values written by lanes 10..19 land at slots 10..19; read via slotB-mapped
        }
        {
            // yr_k lives at slot 10+k; slots 10..13 etc are 8B-aligned only, so remap:
            // read as two float4 + float2 from slot 8.. would misalign; instead lanes wrote
            // bcR[s] and we read slots 10..19 with aligned pairs:
            const float2 p0 = *reinterpret_cast<const float2*>(bcR + 10);
            const float4 p1 = *reinterpret_cast<const float4*>(bcR + 12);
            const float4 p2 = *reinterpret_cast<const float4*>(bcR + 16);
            const float rv[L_DIM] = {p0.x, p0.y, p1.x, p1.y, p1.z, p1.w, p2.x, p2.y, p2.z, p2.w};
#pragma unroll
            for (int k = 0; k < L_DIM; ++k) accN += rv[k] * wgy[k];
        }
        // uo lane fetches its n-column value from the no lane (register crossbar)
        const float nv = __int_as_float(__builtin_amdgcn_ds_bpermute(nperm, __float_as_int(accN)));

        // ---- blend: yn = n + u*(yi - n); stash y_t (f16) for head ----
        const float yn = fmaf(uval, yis - nv, nv);    // meaningful on uo
        yown = yn;
        bcY[s] = yn;
        xprojH[ltraj][t][s] = __float2half(yn);       // xproj[t] consumed above
        SBAR();
        {
            const float4 a = *reinterpret_cast<const float4*>(bcY);
            const float4 b = *reinterpret_cast<const float4*>(bcY + 4);
            const float2 c = *reinterpret_cast<const float2*>(bcY + 8);
            y[0] = a.x; y[1] = a.y; y[2] = a.z; y[3] = a.w;
            y[4] = b.x; y[5] = b.y; y[6] = b.z; y[7] = b.w;
            y[8] = c.x; y[9] = c.y;
        }

        // ---- emitter: logit = b + p_prev . We_p + y . We_y (p already normalized) ----
        float ev = bemit;
#pragma unroll
        for (int q = 0; q < 5; ++q) {
            const float4 z4 = *reinterpret_cast<const float4*>(bcP + q * 4);
            ev += z4.x * waux[q * 4]     + z4.y * waux[q * 4 + 1]
                + z4.z * waux[q * 4 + 2] + z4.w * waux[q * 4 + 3];
        }
#pragma unroll
        for (int k = 0; k < L_DIM; ++k) ev += y[k] * waux[20 + k];
        const float zv = exp2_fast(fminf(ev * LOG2E, 86.0f));

        // producer-side normalization: butterfly sum of zv over the 20 eo lanes
        float zs = eo ? zv : 0.0f;
        zs += __int_as_float(__builtin_amdgcn_ds_swizzle(__float_as_int(zs), 0x041F));
        zs += __int_as_float(__builtin_amdgcn_ds_swizzle(__float_as_int(zs), 0x081F));
        zs += __int_as_float(__builtin_amdgcn_ds_swizzle(__float_as_int(zs), 0x101F));
        zs += __int_as_float(__builtin_amdgcn_ds_swizzle(__float_as_int(zs), 0x201F));
        zs += __int_as_float(__builtin_amdgcn_ds_swizzle(__float_as_int(zs), 0x401F));
        bcP[slotB] = zv * rcp_fast(zs);     // eo -> slots 0..19; others -> unread slots
        SBAR();
    }

    // ================= Phase 3: deferred MLP head =================
    // 32 lanes per traj: group g = s>>3 handles t = g, g+4, ...; col = s&7.
    SBAR();
    {
        const int g = s >> 3, col = s & 7;
        float o8 = 0.0f;
        for (int tb = 0; tb < 15; ++tb) {
            const int t = g + tb * 4;
            const __half2* yh = reinterpret_cast<const __half2*>(&xprojH[ltraj][t][0]);
            const float* wrow = W_mlp + (size_t)t * L_DIM * OUT_DIM + col;
#pragma unroll
            for (int q = 0; q < 5; ++q) {
                const float2 yv = __half22float2(yh[q]);
                o8 += yv.x * wrow[(2 * q) * OUT_DIM] + yv.y * wrow[(2 * q + 1) * OUT_DIM];
            }
        }
        o8 += __shfl_xor(o8, 8, 32);
        o8 += __shfl_xor(o8, 16, 32);
        if (s < OUT_DIM) {
            const float* stp = static_data + (size_t)traj * S_STAT;
            const float* wms = W_mlp + (size_t)(T_STEPS * L_DIM) * OUT_DIM;
#pragma unroll
            for (int i = 0; i < S_STAT; ++i) o8 += stp[i] * wms[i * OUT_DIM + s];
            out[(size_t)traj * OUT_DIM + s] = o8 + b_mlp[s];
        }
    }
}

extern "C" void kernel_launch(void* const* d_in, const int* in_sizes, int n_in,
                              void* d_out, int out_size, void* d_ws, size_t ws_size,
                              hipStream_t stream) {
    const float* data        = (const float*)d_in[0];
    const float* time_steps  = (const float*)d_in[1];
    const float* static_data = (const float*)d_in[2];
    const float* W_update    = (const float*)d_in[3];
    const float* b_update    = (const float*)d_in[4];
    const float* W_reset     = (const float*)d_in[5];
    const float* b_reset     = (const float*)d_in[6];
    const float* W_new       = (const float*)d_in[7];
    const float* b_new       = (const float*)d_in[8];
    const float* W_emit      = (const float*)d_in[9];
    const float* b_emit      = (const float*)d_in[10];
    const float* W_ode       = (const float*)d_in[11];
    const float* b_ode       = (const float*)d_in[12];
    const float* W_mlp       = (const float*)d_in[13];
    const float* b_mlp       = (const float*)d_in[14];
    float* out = (float*)d_out;

    // 8 trajectories per 256-thread block -> 2048 blocks, 8192 waves
    dim3 grid(B_TRAJ / 8), block(256);
    hipLaunchKernelGGL(dgm2_v6, grid, block, 0, stream,
                       data, time_steps, static_data,
                       W_update, b_update, W_reset, b_reset, W_new, b_new,
                       W_emit, b_emit, W_ode, b_ode, W_mlp, b_mlp, out);
}

// Round 2
// 339.832 us; speedup vs baseline: 1.0640x; 1.0640x over previous
//
#include <hip/hip_runtime.h>
#include <hip/hip_fp16.h>
#include <math.h>

// Problem constants (from reference)
#define B_TRAJ 16384
#define T_STEPS 60
#define D_IN 36
#define L_DIM 10
#define C_NUM 20
#define S_STAT 9
#define OUT_DIM 8
#define TT 2
#define NTILE (T_STEPS / TT)   // 30

#define LOG2E 1.4426950408889634f

typedef float f32x2 __attribute__((ext_vector_type(2)));
__device__ __forceinline__ f32x2 pkfma(f32x2 a, f32x2 b, f32x2 c) {
    // llvm.fma.v2f32 -> v_pk_fma_f32 on gfx950 (full-rate packed f32)
    return __builtin_elementwise_fma(a, b, c);
}

__device__ __forceinline__ float rcp_fast(float x) { return __builtin_amdgcn_rcpf(x); }
__device__ __forceinline__ float exp2_fast(float x) { return __builtin_amdgcn_exp2f(x); }
__device__ __forceinline__ float sigm_fast(float x) {
    // 1/(1+2^(-x*log2e)) : mul, exp, add, rcp
    return rcp_fast(1.0f + exp2_fast(x * -LOG2E));
}
__device__ __forceinline__ float tanh_fast(float x) {
    // tanh(x) = 1 - 2/(2^(2x*log2e)+1)
    const float t = fminf(fmaxf(x * (2.0f * LOG2E), -30.0f), 30.0f);
    return fmaf(-2.0f, rcp_fast(exp2_fast(t) + 1.0f), 1.0f);
}
#define WFENCE() __builtin_amdgcn_wave_barrier()

// Phase 1: per-wave precompute xproj[traj][t][c] = bias_c + x_t . Wx[:,c] (f16 in LDS).
// Phase 2: sequential scan (v5 sync skeleton: 4 LDS round-trips, wave_barrier);
//          all dot products as packed f32 (v_pk_fma_f32). ro lanes publish r*yi so
//          the candidate is a plain dot. Softmax z carried UNNORMALIZED (reader zsum
//          via pk_add). y_t written back (f16) into the consumed xproj[t] slot.
// Phase 3: deferred MLP head — 4 t-groups x 8 cols across 32 lanes, 2-shuffle reduce.
// Lane roles (s = lane & 31): s<10 u-col (+ODE col), 10..19 r-col (+emit col),
// 20..29 n-col (+emit col), 30/31 inert. All phase-2/3 sync is intra-wave
// (in-order LDS + wave_barrier).
__global__ __launch_bounds__(256) __attribute__((amdgpu_waves_per_eu(4, 8)))
void dgm2_v7(
    const float* __restrict__ data,        // [B, T, D]
    const float* __restrict__ time_steps,  // [T]
    const float* __restrict__ static_data, // [B, S]
    const float* __restrict__ W_update,    // [46, 10]
    const float* __restrict__ b_update,
    const float* __restrict__ W_reset,     // [46, 10]
    const float* __restrict__ b_reset,
    const float* __restrict__ W_new,       // [46, 10]
    const float* __restrict__ b_new,
    const float* __restrict__ W_emit,      // [30, 20]
    const float* __restrict__ b_emit,
    const float* __restrict__ W_ode,       // [10, 10]
    const float* __restrict__ b_ode,
    const float* __restrict__ W_mlp,       // [609, 8]
    const float* __restrict__ b_mlp,
    float* __restrict__ out)               // [B, 8]
{
    __shared__ __align__(16) __half xprojH[8][61][32];   // 31232 B (t-dim padded: halves 16 banks apart)
    __shared__ __align__(16) float WGX[D_IN][32];        // 4608 B (phase-1 x-weights, col per lane)
    __shared__ __align__(16) float wbuf[4][292];         // 4672 B per-wave scratch:
                                                          //  phase1: xstage [buf][half][tt][36] (288 f)
                                                          //  phase2: bc @ 0/24/48/72 (+half*12), bcP @ 96 (+half*20)
    __shared__ float dts[T_STEPS];

    const int tid  = threadIdx.x;
    const int w    = tid >> 6;
    const int lane = tid & 63;
    const int half = lane >> 5;
    const int s    = lane & 31;
    const int ltraj = w * 2 + half;
    const int traj  = blockIdx.x * 8 + ltraj;

    // ---- block-wide one-time: WGX + dts ----
    for (int i = tid; i < D_IN * 30; i += 256) {
        const int k = i / 30, c = i % 30;
        float v;
        if (c < 10)      v = W_update[(L_DIM + k) * L_DIM + c];
        else if (c < 20) v = W_reset [(L_DIM + k) * L_DIM + (c - 10)];
        else             v = W_new   [(L_DIM + k) * L_DIM + (c - 20)];
        WGX[k][c] = v;
    }
    for (int i = tid; i < D_IN * 2; i += 256) WGX[i >> 1][30 + (i & 1)] = 0.0f;
    if (tid < T_STEPS) dts[tid] = (tid == 0) ? 0.01f : time_steps[tid] - time_steps[tid - 1];
    __syncthreads();

    // per-lane gate-column bias, folded into xproj during phase 1
    float bcol = 0.0f;
    if (s < 10)      bcol = b_update[s];
    else if (s < 20) bcol = b_reset[s - 10];
    else if (s < 30) bcol = b_new[s - 20];

    // ================= Phase 1: xproj precompute (wave-local) =================
    {
        f32x2 wxp2[18];
#pragma unroll
        for (int j = 0; j < 18; ++j) wxp2[j] = (f32x2){WGX[2 * j][s], WGX[2 * j + 1][s]};

        float* xst = &wbuf[w][0];   // [buf][half][tt][36]
        const float* tbase = data + (size_t)(blockIdx.x * 8 + w * 2) * (T_STEPS * D_IN);
        const int sh  = lane / 18;      // staging half
        const int sr  = lane % 18;
        const int stt = sr / 9;         // timestep within tile
        const int sc  = sr % 9;         // float4 chunk
        const bool stg = (lane < 36);

        if (stg) {
            const float4 v = *reinterpret_cast<const float4*>(
                tbase + (size_t)sh * (T_STEPS * D_IN) + stt * D_IN + sc * 4);
            *reinterpret_cast<float4*>(xst + ((0 * 2 + sh) * TT + stt) * 36 + sc * 4) = v;
        }
        WFENCE();

        for (int tile = 0; tile < NTILE; ++tile) {
            const int cb = tile & 1, nb = cb ^ 1;
            float4 pf = make_float4(0.f, 0.f, 0.f, 0.f);
            if (stg && (tile + 1 < NTILE)) {
                pf = *reinterpret_cast<const float4*>(
                    tbase + (size_t)sh * (T_STEPS * D_IN) + ((tile + 1) * TT + stt) * D_IN + sc * 4);
            }
#pragma unroll
            for (int tt = 0; tt < TT; ++tt) {
                const float* xrow = xst + ((cb * 2 + half) * TT + tt) * 36;
                f32x2 acc2 = (f32x2){bcol, 0.0f};       // gate bias folded here
#pragma unroll
                for (int c = 0; c < 9; ++c) {
                    const float4 x4 = *reinterpret_cast<const float4*>(xrow + c * 4);
                    acc2 = pkfma((f32x2){x4.x, x4.y}, wxp2[2 * c],     acc2);
                    acc2 = pkfma((f32x2){x4.z, x4.w}, wxp2[2 * c + 1], acc2);
                }
                if (s < 30) xprojH[ltraj][tile * TT + tt][s] = __float2half(acc2.x + acc2.y);
            }
            if (stg && (tile + 1 < NTILE)) {
                *reinterpret_cast<float4*>(xst + ((nb * 2 + sh) * TT + stt) * 36 + sc * 4) = pf;
            }
            WFENCE();
        }
    }

    // ================= Phase 2: sequential scan =================
    const bool uo = (s < 10);
    const bool ro = (s >= 10 && s < 20);
    const bool no = (s >= 20 && s < 30);
    const bool eo = (s >= 10 && s < 30);
    const int  gcol = uo ? s : (ro ? (s - 10) : (no ? (s - 20) : 0));

    const float* Wg = uo ? W_update : (ro ? W_reset : W_new);
    f32x2 wgy2[5];
#pragma unroll
    for (int j = 0; j < 5; ++j) {
        const float w0 = (s < 30) ? Wg[(2 * j)     * L_DIM + gcol] : 0.0f;
        const float w1 = (s < 30) ? Wg[(2 * j + 1) * L_DIM + gcol] : 0.0f;
        wgy2[j] = (f32x2){w0, w1};
    }

    f32x2 waux2[15];    // eo: emit col (pairs 0..9 = z-part, 10..14 = y-part); uo: 0..4 = ODE col
#pragma unroll
    for (int j = 0; j < 15; ++j) {
        float v0 = 0.0f, v1 = 0.0f;
        if (eo)            { v0 = W_emit[(2 * j) * C_NUM + (s - 10)];
                             v1 = W_emit[(2 * j + 1) * C_NUM + (s - 10)]; }
        else if (uo && j < 5) { v0 = W_ode[(2 * j) * L_DIM + s];
                                v1 = W_ode[(2 * j + 1) * L_DIM + s]; }
        waux2[j] = (f32x2){v0, v1};
    }
    const float bode  = uo ? b_ode[s] : 0.0f;
    const float bemit = eo ? b_emit[s - 10] : 0.0f;

    // per-wave bc views inside wbuf (identical layout to v5)
    float* bcYI = &wbuf[w][0]  + half * 12;
    float* bcR  = &wbuf[w][24] + half * 12;
    float* bcN  = &wbuf[w][48] + half * 12;
    float* bcY  = &wbuf[w][72] + half * 12;
    float* bcP  = &wbuf[w][96] + half * 20;

    f32x2 y2[5];
#pragma unroll
    for (int k = 0; k < 5; ++k) y2[k] = (f32x2){0.0f, 0.0f};
    float yown = 0.0f;
    if (eo) bcP[s - 10] = 0.0f;     // carried unnormalized z; 0 => p=0 at t=0
    WFENCE();

    for (int t = 0; t < T_STEPS; ++t) {
        const float dt = dts[t];

        // ---- ODE: yi_s = y_s + tanh(b + y.Wode_col_s)*dt (uo lanes) ----
        f32x2 g2 = (f32x2){bode, 0.0f};
#pragma unroll
        for (int k = 0; k < 5; ++k) g2 = pkfma(y2[k], waux2[k], g2);
        const float yis = fmaf(tanh_fast(g2.x + g2.y), dt, yown);
        if (uo) bcYI[s] = yis;
        WFENCE();
        {
            const float4 a = *reinterpret_cast<const float4*>(bcYI);
            const float4 b = *reinterpret_cast<const float4*>(bcYI + 4);
            const float2 c = *reinterpret_cast<const float2*>(bcYI + 8);
            y2[0] = (f32x2){a.x, a.y}; y2[1] = (f32x2){a.z, a.w};
            y2[2] = (f32x2){b.x, b.y}; y2[3] = (f32x2){b.z, b.w};
            y2[4] = (f32x2){c.x, c.y};
        }
        // ro lane's own yi: scalar LDS read, parallel with the vector reads above
        const float yi_r = bcYI[gcol];

        // ---- gates: pre-activation = xproj(f16, bias folded) + y-part ----
        const float xa = __half2float(xprojH[ltraj][t][s]);
        f32x2 ay2 = (f32x2){xa, 0.0f};
#pragma unroll
        for (int k = 0; k < 5; ++k) ay2 = pkfma(y2[k], wgy2[k], ay2);
        const float uval = sigm_fast(ay2.x + ay2.y);   // u on uo, r on ro
        if (ro) bcR[s - 10] = uval * yi_r;             // publish yr_k = r_k * yi_k
        WFENCE();

        // ---- candidate: xa + sum yr_k wn_k ----
        f32x2 n2 = (f32x2){xa, 0.0f};
        {
            const float4 a = *reinterpret_cast<const float4*>(bcR);
            const float4 b = *reinterpret_cast<const float4*>(bcR + 4);
            const float2 c = *reinterpret_cast<const float2*>(bcR + 8);
            n2 = pkfma((f32x2){a.x, a.y}, wgy2[0], n2);
            n2 = pkfma((f32x2){a.z, a.w}, wgy2[1], n2);
            n2 = pkfma((f32x2){b.x, b.y}, wgy2[2], n2);
            n2 = pkfma((f32x2){b.z, b.w}, wgy2[3], n2);
            n2 = pkfma((f32x2){c.x, c.y}, wgy2[4], n2);
        }
        const float accN = n2.x + n2.y;
        if (no) bcN[s - 20] = accN;
        WFENCE();

        // ---- blend on u lanes: yn = n + u*(yi - n); stash y_t (f16) for head ----
        if (uo) {
            const float nv = bcN[s];
            const float yn = fmaf(uval, yis - nv, nv);
            yown = yn;
            bcY[s] = yn;
            xprojH[ltraj][t][s] = __float2half(yn);   // xproj[t] consumed above
        }
        WFENCE();
        {
            const float4 a = *reinterpret_cast<const float4*>(bcY);
            const float4 b = *reinterpret_cast<const float4*>(bcY + 4);
            const float2 c = *reinterpret_cast<const float2*>(bcY + 8);
            y2[0] = (f32x2){a.x, a.y}; y2[1] = (f32x2){a.z, a.w};
            y2[2] = (f32x2){b.x, b.y}; y2[3] = (f32x2){b.z, b.w};
            y2[4] = (f32x2){c.x, c.y};
        }

        // ---- emitter: logit = b + (z_prev . We_p)/sum(z_prev) + y . We_y ----
        f32x2 zd2 = (f32x2){0.0f, 0.0f};
        f32x2 zs2 = (f32x2){0.0f, 0.0f};
#pragma unroll
        for (int q = 0; q < 5; ++q) {
            const float4 z4 = *reinterpret_cast<const float4*>(bcP + q * 4);
            const f32x2 za = (f32x2){z4.x, z4.y};
            const f32x2 zb = (f32x2){z4.z, z4.w};
            zd2 = pkfma(za, waux2[2 * q],     zd2);
            zd2 = pkfma(zb, waux2[2 * q + 1], zd2);
            zs2 = zs2 + za + zb;
        }
        const float zsum = zs2.x + zs2.y;
        const float pinv = (t == 0) ? 0.0f : rcp_fast(zsum);
        f32x2 ev2 = (f32x2){fmaf(zd2.x + zd2.y, pinv, bemit), 0.0f};
#pragma unroll
        for (int k = 0; k < 5; ++k) ev2 = pkfma(y2[k], waux2[10 + k], ev2);
        const float zv = exp2_fast(fminf((ev2.x + ev2.y) * LOG2E, 86.0f));
        if (eo) bcP[s - 10] = zv;
        WFENCE();
    }

    // ================= Phase 3: deferred MLP head =================
    // 32 lanes per traj: group g = s>>3 handles t = g, g+4, ...; col = s&7.
    WFENCE();
    {
        const int g = s >> 3, col = s & 7;
        f32x2 o2 = (f32x2){0.0f, 0.0f};
        for (int tb = 0; tb < 15; ++tb) {
            const int t = g + tb * 4;
            const __half2* yh = reinterpret_cast<const __half2*>(&xprojH[ltraj][t][0]);
            const float* wrow = W_mlp + (size_t)t * L_DIM * OUT_DIM + col;
#pragma unroll
            for (int q = 0; q < 5; ++q) {
                const float2 yv = __half22float2(yh[q]);
                const f32x2 w2 = (f32x2){wrow[(2 * q) * OUT_DIM], wrow[(2 * q + 1) * OUT_DIM]};
                o2 = pkfma((f32x2){yv.x, yv.y}, w2, o2);
            }
        }
        float o8 = o2.x + o2.y;
        o8 += __shfl_xor(o8, 8, 32);
        o8 += __shfl_xor(o8, 16, 32);
        if (s < OUT_DIM) {
            const float* stp = static_data + (size_t)traj * S_STAT;
            const float* wms = W_mlp + (size_t)(T_STEPS * L_DIM) * OUT_DIM;
#pragma unroll
            for (int i = 0; i < S_STAT; ++i) o8 += stp[i] * wms[i * OUT_DIM + s];
            out[(size_t)traj * OUT_DIM + s] = o8 + b_mlp[s];
        }
    }
}

extern "C" void kernel_launch(void* const* d_in, const int* in_sizes, int n_in,
                              void* d_out, int out_size, void* d_ws, size_t ws_size,
                              hipStream_t stream) {
    const float* data        = (const float*)d_in[0];
    const float* time_steps  = (const float*)d_in[1];
    const float* static_data = (const float*)d_in[2];
    const float* W_update    = (const float*)d_in[3];
    const float* b_update    = (const float*)d_in[4];
    const float* W_reset     = (const float*)d_in[5];
    const float* b_reset     = (const float*)d_in[6];
    const float* W_new       = (const float*)d_in[7];
    const float* b_new       = (const float*)d_in[8];
    const float* W_emit      = (const float*)d_in[9];
    const float* b_emit      = (const float*)d_in[10];
    const float* W_ode       = (const float*)d_in[11];
    const float* b_ode       = (const float*)d_in[12];
    const float* W_mlp       = (const float*)d_in[13];
    const float* b_mlp       = (const float*)d_in[14];
    float* out = (float*)d_out;

    // 8 trajectories per 256-thread block -> 2048 blocks, 8192 waves
    dim3 grid(B_TRAJ / 8), block(256);
    hipLaunchKernelGGL(dgm2_v7, grid, block, 0, stream,
                       data, time_steps, static_data,
                       W_update, b_update, W_reset, b_reset, W_new, b_new,
                       W_emit, b_emit, W_ode, b_ode, W_mlp, b_mlp, out);
}

// Round 4
// 330.563 us; speedup vs baseline: 1.0938x; 1.0280x over previous
//
#include <hip/hip_runtime.h>
#include <hip/hip_fp16.h>
#include <math.h>

// Problem constants (from reference)
#define B_TRAJ 16384
#define T_STEPS 60
#define D_IN 36
#define L_DIM 10
#define C_NUM 20
#define S_STAT 9
#define OUT_DIM 8
#define TT 2
#define NTILE (T_STEPS / TT)   // 30
#define XTS 1824               // per-traj xproj stride in halves: 60*30 data + 24 pad
                               // -> 3648 B stride; 3648 mod 128 = 64 => adjacent trajs
                               //    (the two halves of a wave) sit 16 banks apart.

#define LOG2E 1.4426950408889634f

typedef float f32x2 __attribute__((ext_vector_type(2)));
__device__ __forceinline__ f32x2 pkfma(f32x2 a, f32x2 b, f32x2 c) {
    // llvm.fma.v2f32 -> v_pk_fma_f32 on gfx950 (full-rate packed f32)
    return __builtin_elementwise_fma(a, b, c);
}

__device__ __forceinline__ float rcp_fast(float x) { return __builtin_amdgcn_rcpf(x); }
__device__ __forceinline__ float exp2_fast(float x) { return __builtin_amdgcn_exp2f(x); }
__device__ __forceinline__ float sigm_fast(float x) {
    return rcp_fast(1.0f + exp2_fast(x * -LOG2E));
}
__device__ __forceinline__ float tanh_fast(float x) {
    const float t = fminf(fmaxf(x * (2.0f * LOG2E), -30.0f), 30.0f);
    return fmaf(-2.0f, rcp_fast(exp2_fast(t) + 1.0f), 1.0f);
}
#define WFENCE() __builtin_amdgcn_wave_barrier()

// v8: LDS squeezed under 32 KiB -> 5 blocks/CU (was 4), and the per-step serial
// LDS chain cut from 4 round-trips to 3 (blend moved onto the n-lanes; u is
// published in the same fence as r*yi, bcN round-trip deleted).
// Phase 1: per-wave xproj[traj][t][c] = bias_c + x_t . Wx[:,c] (f16, 30-col rows),
//          single LDS staging buffer + register-held prefetch; weights direct
//          from global (WGX table removed).
// Phase 2: scan with 3 carry round-trips (YI, R+U, Y) + off-path P chain.
// Phase 3: deferred MLP head (unchanged).
// Lane roles (s = lane & 31): s<10 u-col (+ODE col), 10..19 r-col (+emit col),
// 20..29 n-col (+emit col, blend+stash), 30/31 inert.
__global__ __launch_bounds__(256) __attribute__((amdgpu_waves_per_eu(4, 8)))
void dgm2_v8(
    const float* __restrict__ data,        // [B, T, D]
    const float* __restrict__ time_steps,  // [T]
    const float* __restrict__ static_data, // [B, S]
    const float* __restrict__ W_update,    // [46, 10]
    const float* __restrict__ b_update,
    const float* __restrict__ W_reset,     // [46, 10]
    const float* __restrict__ b_reset,
    const float* __restrict__ W_new,       // [46, 10]
    const float* __restrict__ b_new,
    const float* __restrict__ W_emit,      // [30, 20]
    const float* __restrict__ b_emit,
    const float* __restrict__ W_ode,       // [10, 10]
    const float* __restrict__ b_ode,
    const float* __restrict__ W_mlp,       // [609, 8]
    const float* __restrict__ b_mlp,
    float* __restrict__ out)               // [B, 8]
{
    __shared__ __align__(16) __half xprojH[8 * XTS];   // 29184 B
    __shared__ __align__(16) float wbuf[4][144];       // 2304 B per-wave scratch:
                                                        //  phase1: xstage [half][tt][36] (144 f)
                                                        //  phase2: bcYI@0 bcR@24 bcU@48 bcY@72 (+half*12), bcP@96 (+half*20)
    __shared__ float dts[T_STEPS];                     // 240 B  => total 31728 B -> 5 blocks/CU

    const int tid  = threadIdx.x;
    const int w    = tid >> 6;
    const int lane = tid & 63;
    const int half = lane >> 5;
    const int s    = lane & 31;
    const int ltraj = w * 2 + half;
    const int traj  = blockIdx.x * 8 + ltraj;
    __half* xpj = xprojH + ltraj * XTS;

    if (tid < T_STEPS) dts[tid] = (tid == 0) ? 0.01f : time_steps[tid] - time_steps[tid - 1];
    __syncthreads();

    // lane roles
    const bool uo = (s < 10);
    const bool ro = (s >= 10 && s < 20);
    const bool no = (s >= 20 && s < 30);
    const bool eo = (s >= 10 && s < 30);
    const int  gcol = uo ? s : (ro ? (s - 10) : (no ? (s - 20) : 0));
    const float* Wg = uo ? W_update : (ro ? W_reset : W_new);   // s>=30 -> W_new col 0 (harmless)

    // per-lane gate-column bias, folded into xproj during phase 1
    float bcol = 0.0f;
    if (uo)      bcol = b_update[s];
    else if (ro) bcol = b_reset[s - 10];
    else if (no) bcol = b_new[s - 20];

    // ================= Phase 1: xproj precompute (wave-local) =================
    {
        f32x2 wxp2[18];   // x-part rows 10..45 of this lane's gate column, direct from global
#pragma unroll
        for (int j = 0; j < 18; ++j)
            wxp2[j] = (f32x2){Wg[(L_DIM + 2 * j) * L_DIM + gcol],
                              Wg[(L_DIM + 2 * j + 1) * L_DIM + gcol]};

        float* xst = &wbuf[w][0];   // [half][tt][36], single buffer
        const float* tbase = data + (size_t)(blockIdx.x * 8 + w * 2) * (T_STEPS * D_IN);
        const int sh  = lane / 18;      // staging half
        const int sr  = lane % 18;
        const int stt = sr / 9;         // timestep within tile
        const int sc  = sr % 9;         // float4 chunk
        const bool stg = (lane < 36);

        if (stg) {
            const float4 v = *reinterpret_cast<const float4*>(
                tbase + (size_t)sh * (T_STEPS * D_IN) + stt * D_IN + sc * 4);
            *reinterpret_cast<float4*>(xst + (sh * TT + stt) * 36 + sc * 4) = v;
        }
        WFENCE();

        for (int tile = 0; tile < NTILE; ++tile) {
            float4 pf = make_float4(0.f, 0.f, 0.f, 0.f);
            const bool more = stg && (tile + 1 < NTILE);
            if (more) {
                pf = *reinterpret_cast<const float4*>(
                    tbase + (size_t)sh * (T_STEPS * D_IN) + ((tile + 1) * TT + stt) * D_IN + sc * 4);
            }
#pragma unroll
            for (int tt = 0; tt < TT; ++tt) {
                const float* xrow = xst + (half * TT + tt) * 36;
                f32x2 acc2 = (f32x2){bcol, 0.0f};   // gate bias folded here
#pragma unroll
                for (int c = 0; c < 9; ++c) {
                    const float4 x4 = *reinterpret_cast<const float4*>(xrow + c * 4);
                    acc2 = pkfma((f32x2){x4.x, x4.y}, wxp2[2 * c],     acc2);
                    acc2 = pkfma((f32x2){x4.z, x4.w}, wxp2[2 * c + 1], acc2);
                }
                if (s < 30) xpj[(tile * TT + tt) * 30 + s] = __float2half(acc2.x + acc2.y);
            }
            WFENCE();   // all lanes done reading this tile before overwrite
            if (more) {
                *reinterpret_cast<float4*>(xst + (sh * TT + stt) * 36 + sc * 4) = pf;
            }
            WFENCE();   // staged writes visible before next tile's reads
        }
    }

    // ================= Phase 2: sequential scan =================
    f32x2 wgy2[5];   // y-part (rows 0..9) of this lane's gate column
#pragma unroll
    for (int j = 0; j < 5; ++j)
        wgy2[j] = (f32x2){Wg[(2 * j) * L_DIM + gcol], Wg[(2 * j + 1) * L_DIM + gcol]};

    f32x2 waux2[15];    // eo: emit col (0..9 = z-part rows 0..19, 10..14 = y-part rows 20..29); uo: 0..4 = ODE col
#pragma unroll
    for (int j = 0; j < 15; ++j) {
        float v0 = 0.0f, v1 = 0.0f;
        if (eo)               { v0 = W_emit[(2 * j) * C_NUM + (s - 10)];
                                v1 = W_emit[(2 * j + 1) * C_NUM + (s - 10)]; }
        else if (uo && j < 5) { v0 = W_ode[(2 * j) * L_DIM + s];
                                v1 = W_ode[(2 * j + 1) * L_DIM + s]; }
        waux2[j] = (f32x2){v0, v1};
    }
    const float bode  = uo ? b_ode[s] : 0.0f;
    const float bemit = eo ? b_emit[s - 10] : 0.0f;

    // per-wave bc views inside wbuf
    float* wb   = &wbuf[w][0];
    float* bcYI = wb + 0  + half * 12;
    float* bcR  = wb + 24 + half * 12;
    float* bcU  = wb + 48 + half * 12;
    float* bcY  = wb + 72 + half * 12;
    float* bcP  = wb + 96 + half * 20;

    f32x2 y2[5];
#pragma unroll
    for (int k = 0; k < 5; ++k) y2[k] = (f32x2){0.0f, 0.0f};
    float yown = 0.0f;
    if (eo) bcP[s - 10] = 0.0f;     // carried unnormalized z; 0 => p=0 at t=0
    WFENCE();

    for (int t = 0; t < T_STEPS; ++t) {
        const float dt = dts[t];

        // ---- ODE: yi_s = y_s + tanh(b + y.Wode_col_s)*dt (meaningful on uo) ----
        f32x2 g2 = (f32x2){bode, 0.0f};
#pragma unroll
        for (int k = 0; k < 5; ++k) g2 = pkfma(y2[k], waux2[k], g2);
        const float yis = fmaf(tanh_fast(g2.x + g2.y), dt, yown);
        if (uo) bcYI[s] = yis;
        WFENCE();
        {
            const float4 a = *reinterpret_cast<const float4*>(bcYI);
            const float4 b = *reinterpret_cast<const float4*>(bcYI + 4);
            const float2 c = *reinterpret_cast<const float2*>(bcYI + 8);
            y2[0] = (f32x2){a.x, a.y}; y2[1] = (f32x2){a.z, a.w};
            y2[2] = (f32x2){b.x, b.y}; y2[3] = (f32x2){b.z, b.w};
            y2[4] = (f32x2){c.x, c.y};
        }
        const float yi_g = bcYI[gcol];   // this lane's own column yi (scalar, parallel read)

        // ---- gates: pre-activation = xproj(f16, bias folded) + yi-part ----
        const float xa = __half2float(xpj[t * 30 + s]);   // s>=30 reads pad/next-row, never used
        f32x2 ay2 = (f32x2){xa, 0.0f};
#pragma unroll
        for (int k = 0; k < 5; ++k) ay2 = pkfma(y2[k], wgy2[k], ay2);
        const float uval = sigm_fast(ay2.x + ay2.y);   // u on uo, r on ro
        if (ro) bcR[s - 10] = uval * yi_g;             // publish yr_k = r_k * yi_k
        if (uo) bcU[s] = uval;                         // publish u_k (same fence)
        WFENCE();

        // ---- candidate + blend on n-lanes: yn = n + u*(yi - n) ----
        f32x2 n2 = (f32x2){xa, 0.0f};
        {
            const float4 a = *reinterpret_cast<const float4*>(bcR);
            const float4 b = *reinterpret_cast<const float4*>(bcR + 4);
            const float2 c = *reinterpret_cast<const float2*>(bcR + 8);
            n2 = pkfma((f32x2){a.x, a.y}, wgy2[0], n2);
            n2 = pkfma((f32x2){a.z, a.w}, wgy2[1], n2);
            n2 = pkfma((f32x2){b.x, b.y}, wgy2[2], n2);
            n2 = pkfma((f32x2){b.z, b.w}, wgy2[3], n2);
            n2 = pkfma((f32x2){c.x, c.y}, wgy2[4], n2);
        }
        const float accN = n2.x + n2.y;
        const float u_n  = bcU[gcol];                  // n-lane k reads u_k
        const float yn   = fmaf(u_n, yi_g - accN, accN);
        if (no) {
            bcY[s - 20] = yn;
            xpj[t * 30 + (s - 20)] = __float2half(yn); // stash y_t (f16) for head
        }
        WFENCE();
        {
            const float4 a = *reinterpret_cast<const float4*>(bcY);
            const float4 b = *reinterpret_cast<const float4*>(bcY + 4);
            const float2 c = *reinterpret_cast<const float2*>(bcY + 8);
            y2[0] = (f32x2){a.x, a.y}; y2[1] = (f32x2){a.z, a.w};
            y2[2] = (f32x2){b.x, b.y}; y2[3] = (f32x2){b.z, b.w};
            y2[4] = (f32x2){c.x, c.y};
        }
        yown = bcY[gcol];                              // carry for next ODE (uo)

        // ---- emitter: logit = b + (z_prev . We_p)/sum(z_prev) + y . We_y ----
        f32x2 zd2 = (f32x2){0.0f, 0.0f};
        f32x2 zs2 = (f32x2){0.0f, 0.0f};
#pragma unroll
        for (int q = 0; q < 5; ++q) {
            const float4 z4 = *reinterpret_cast<const float4*>(bcP + q * 4);
            const f32x2 za = (f32x2){z4.x, z4.y};
            const f32x2 zb = (f32x2){z4.z, z4.w};
            zd2 = pkfma(za, waux2[2 * q],     zd2);
            zd2 = pkfma(zb, waux2[2 * q + 1], zd2);
            zs2 = zs2 + za + zb;
        }
        const float zsum = zs2.x + zs2.y;
        const float pinv = (t == 0) ? 0.0f : rcp_fast(zsum);
        f32x2 ev2 = (f32x2){fmaf(zd2.x + zd2.y, pinv, bemit), 0.0f};
#pragma unroll
        for (int k = 0; k < 5; ++k) ev2 = pkfma(y2[k], waux2[10 + k], ev2);
        const float zv = exp2_fast(fminf((ev2.x + ev2.y) * LOG2E, 86.0f));
        if (eo) bcP[s - 10] = zv;
        // no end-of-step fence: next-iter P read sits behind that iter's 3 fences;
        // all other cross-iteration DS pairs are provably disjoint regions.
    }

    // ================= Phase 3: deferred MLP head =================
    // 32 lanes per traj: group g = s>>3 handles t = g, g+4, ...; col = s&7.
    WFENCE();
    {
        const int g = s >> 3, col = s & 7;
        f32x2 o2 = (f32x2){0.0f, 0.0f};
        for (int tb = 0; tb < 15; ++tb) {
            const int t = g + tb * 4;
            const __half2* yh = reinterpret_cast<const __half2*>(xpj + t * 30);
            const float* wrow = W_mlp + (size_t)t * L_DIM * OUT_DIM + col;
#pragma unroll
            for (int q = 0; q < 5; ++q) {
                const float2 yv = __half22float2(yh[q]);
                const f32x2 w2 = (f32x2){wrow[(2 * q) * OUT_DIM], wrow[(2 * q + 1) * OUT_DIM]};
                o2 = pkfma((f32x2){yv.x, yv.y}, w2, o2);
            }
        }
        float o8 = o2.x + o2.y;
        o8 += __shfl_xor(o8, 8, 32);
        o8 += __shfl_xor(o8, 16, 32);
        if (s < OUT_DIM) {
            const float* stp = static_data + (size_t)traj * S_STAT;
            const float* wms = W_mlp + (size_t)(T_STEPS * L_DIM) * OUT_DIM;
#pragma unroll
            for (int i = 0; i < S_STAT; ++i) o8 += stp[i] * wms[i * OUT_DIM + s];
            out[(size_t)traj * OUT_DIM + s] = o8 + b_mlp[s];
        }
    }
}

extern "C" void kernel_launch(void* const* d_in, const int* in_sizes, int n_in,
                              void* d_out, int out_size, void* d_ws, size_t ws_size,
                              hipStream_t stream) {
    const float* data        = (const float*)d_in[0];
    const float* time_steps  = (const float*)d_in[1];
    const float* static_data = (const float*)d_in[2];
    const float* W_update    = (const float*)d_in[3];
    const float* b_update    = (const float*)d_in[4];
    const float* W_reset     = (const float*)d_in[5];
    const float* b_reset     = (const float*)d_in[6];
    const float* W_new       = (const float*)d_in[7];
    const float* b_new       = (const float*)d_in[8];
    const float* W_emit      = (const float*)d_in[9];
    const float* b_emit      = (const float*)d_in[10];
    const float* W_ode       = (const float*)d_in[11];
    const float* b_ode       = (const float*)d_in[12];
    const float* W_mlp       = (const float*)d_in[13];
    const float* b_mlp       = (const float*)d_in[14];
    float* out = (float*)d_out;

    // 8 trajectories per 256-thread block -> 2048 blocks, 8192 waves
    dim3 grid(B_TRAJ / 8), block(256);
    hipLaunchKernelGGL(dgm2_v8, grid, block, 0, stream,
                       data, time_steps, static_data,
                       W_update, b_update, W_reset, b_reset, W_new, b_new,
                       W_emit, b_emit, W_ode, b_ode, W_mlp, b_mlp, out);
}